// Round 3
// baseline (345.967 us; speedup 1.0000x reference)
//
#include <hip/hip_runtime.h>

#define BATCH 16384
#define LSEQ  50
#define DIN   20
#define CHN   16
#define HID   6

__device__ __forceinline__ float frcp(float x){ return __builtin_amdgcn_rcpf(x); }
__device__ __forceinline__ float fsig(float x){ return frcp(1.0f + __expf(-x)); }
__device__ __forceinline__ float ftanh(float x){ float t = __expf(2.0f*x); return (t - 1.0f) * frcp(t + 1.0f); }
__device__ __forceinline__ float lrelu(float v){ return v > 0.0f ? v : 0.1f*v; }

// ---------------- K1: per-row embed. xe[16] and gi[18] for each (b,l) row ----------------
// xeg layout: [B*L][16] flat (== xe_flat[b][800]); gig layout: [B*L][20] (18 used, 16B-aligned rows)
__global__ __launch_bounds__(256) void k_embed(
    const float* __restrict__ x,
    const float* __restrict__ we_w, const float* __restrict__ we_b,
    const float* __restrict__ wih,  const float* __restrict__ bih,
    float* __restrict__ xeg, float* __restrict__ gig)
{
  const size_t r = (size_t)blockIdx.x * 256 + threadIdx.x;   // [0, B*L)
  float xv[DIN];
  const float4* xr = (const float4*)(x + r * DIN);
  #pragma unroll
  for (int q = 0; q < 5; ++q) {
    float4 v = xr[q];
    xv[4*q] = v.x; xv[4*q+1] = v.y; xv[4*q+2] = v.z; xv[4*q+3] = v.w;
  }
  float xe[CHN];
  #pragma unroll
  for (int c = 0; c < CHN; ++c) {
    float a = we_b[c];
    #pragma unroll
    for (int d = 0; d < DIN; ++d) a = fmaf(xv[d], we_w[c * DIN + d], a);
    xe[c] = a;
  }
  float4* xo = (float4*)(xeg + r * CHN);
  xo[0] = make_float4(xe[0],  xe[1],  xe[2],  xe[3]);
  xo[1] = make_float4(xe[4],  xe[5],  xe[6],  xe[7]);
  xo[2] = make_float4(xe[8],  xe[9],  xe[10], xe[11]);
  xo[3] = make_float4(xe[12], xe[13], xe[14], xe[15]);
  float gi[18];
  #pragma unroll
  for (int g = 0; g < 18; ++g) {
    float a = bih[g];
    #pragma unroll
    for (int c = 0; c < CHN; ++c) a = fmaf(xe[c], wih[g * CHN + c], a);
    gi[g] = a;
  }
  float* go = gig + r * 20;
  ((float4*)go)[0] = make_float4(gi[0],  gi[1],  gi[2],  gi[3]);
  ((float4*)go)[1] = make_float4(gi[4],  gi[5],  gi[6],  gi[7]);
  ((float4*)go)[2] = make_float4(gi[8],  gi[9],  gi[10], gi[11]);
  ((float4*)go)[3] = make_float4(gi[12], gi[13], gi[14], gi[15]);
  *(float2*)(go + 16) = make_float2(gi[16], gi[17]);
}

// ---------------- K2: GRU, one element per lane (64 elements/wave, 1 wave/block) ----------------
__global__ __launch_bounds__(64) void k_gru(
    const float* __restrict__ gig,
    const float* __restrict__ whh, const float* __restrict__ bhh,
    float* __restrict__ x4g)
{
  const int b = blockIdx.x * 64 + threadIdx.x;
  float wh[18][HID];
  #pragma unroll
  for (int g = 0; g < 18; ++g)
    #pragma unroll
    for (int k = 0; k < HID; ++k) wh[g][k] = whh[g * HID + k];
  float bh[18];
  #pragma unroll
  for (int g = 0; g < 18; ++g) bh[g] = bhh[g];

  const float* gp = gig + (size_t)b * (LSEQ * 20);
  float* op = x4g + (size_t)b * (LSEQ * HID);

  float h[HID];
  #pragma unroll
  for (int k = 0; k < HID; ++k) h[k] = 0.0f;

  float cur[18];
  {
    const float4* q = (const float4*)gp;
    float4 a0 = q[0], a1 = q[1], a2 = q[2], a3 = q[3];
    float2 a4 = *(const float2*)(gp + 16);
    cur[0]=a0.x; cur[1]=a0.y; cur[2]=a0.z; cur[3]=a0.w;
    cur[4]=a1.x; cur[5]=a1.y; cur[6]=a1.z; cur[7]=a1.w;
    cur[8]=a2.x; cur[9]=a2.y; cur[10]=a2.z; cur[11]=a2.w;
    cur[12]=a3.x; cur[13]=a3.y; cur[14]=a3.z; cur[15]=a3.w;
    cur[16]=a4.x; cur[17]=a4.y;
  }

  for (int l = 0; l < LSEQ; ++l) {
    float nxt[18];
    if (l < LSEQ - 1) {                     // prefetch next gi row
      const float* np = gp + (l + 1) * 20;
      const float4* q = (const float4*)np;
      float4 a0 = q[0], a1 = q[1], a2 = q[2], a3 = q[3];
      float2 a4 = *(const float2*)(np + 16);
      nxt[0]=a0.x; nxt[1]=a0.y; nxt[2]=a0.z; nxt[3]=a0.w;
      nxt[4]=a1.x; nxt[5]=a1.y; nxt[6]=a1.z; nxt[7]=a1.w;
      nxt[8]=a2.x; nxt[9]=a2.y; nxt[10]=a2.z; nxt[11]=a2.w;
      nxt[12]=a3.x; nxt[13]=a3.y; nxt[14]=a3.z; nxt[15]=a3.w;
      nxt[16]=a4.x; nxt[17]=a4.y;
    }
    float gh[18];
    #pragma unroll
    for (int g = 0; g < 18; ++g) {
      float a = bh[g];
      #pragma unroll
      for (int k = 0; k < HID; ++k) a = fmaf(wh[g][k], h[k], a);
      gh[g] = a;
    }
    float r6[HID], z6[HID];
    #pragma unroll
    for (int m = 0; m < HID; ++m) r6[m] = fsig(cur[m] + gh[m]);
    #pragma unroll
    for (int m = 0; m < HID; ++m) z6[m] = fsig(cur[6 + m] + gh[6 + m]);
    #pragma unroll
    for (int m = 0; m < HID; ++m) {
      float n = ftanh(fmaf(r6[m], gh[12 + m], cur[12 + m]));
      h[m] = fmaf(z6[m], h[m] - n, n);      // (1-z)*n + z*h
    }
    *(float2*)(op + l * HID)     = make_float2(h[0], h[1]);
    *(float2*)(op + l * HID + 2) = make_float2(h[2], h[3]);
    *(float2*)(op + l * HID + 4) = make_float2(h[4], h[5]);
    #pragma unroll
    for (int g = 0; g < 18; ++g) cur[g] = nxt[g];
  }
}

// ---------------- K3: per-element wave — attn, convs, score-softmax, fc ----------------
// Per-wave LDS slab (floats), SLAB = 2368 -> 9472 B/wave, 37888 B/block = 4 blocks/CU.
//  [0,800)     sXE : xe flat (l*16+c); after conv: sY aliases [400,700)
//  [800,1600)  R1  : sAT [50][16] -> sC [50][16] rows {T[0..5], -, WX[8..13]}
//  [1600,1904) sX4 : x4 flat (l*6+h)
//  [1904,2304) sX4P: x4 padded [50][8]
//  [2304,2360) sFE : feat[54]
constexpr int SLAB3 = 2368;

__global__ __launch_bounds__(256, 4) void k_tail(
    const float* __restrict__ xeg, const float* __restrict__ x4g,
    const float* __restrict__ attn_w, const float* __restrict__ attn_b,
    const float* __restrict__ c1w, const float* __restrict__ c1b,
    const float* __restrict__ c2w, const float* __restrict__ c2b,
    const float* __restrict__ c3w, const float* __restrict__ c3b,
    const float* __restrict__ fc3w, const float* __restrict__ fc3b,
    float* __restrict__ out)
{
  __shared__ __align__(16) float smem[4 * SLAB3];
  const int tid  = threadIdx.x;
  const int wave = tid >> 6;
  const int lane = tid & 63;
  const int b    = blockIdx.x * 4 + wave;

  float* S    = smem + wave * SLAB3;
  float* sXE  = S;
  float* sY   = S + 400;
  float* R1   = S + 800;
  float* sX4  = S + 1600;
  float* sX4P = S + 1904;
  float* sFE  = S + 2304;

  // ---- stage xe (200 f4) and x4 (75 f4) into LDS ----
  {
    const float4* xs = (const float4*)(xeg + (size_t)b * 800);
    float4* xd = (float4*)sXE;
    #pragma unroll
    for (int q = 0; q < 3; ++q) xd[lane + 64 * q] = xs[lane + 64 * q];
    if (lane < 8) xd[lane + 192] = xs[lane + 192];
    const float4* hs = (const float4*)(x4g + (size_t)b * 300);
    float4* hd = (float4*)sX4;
    hd[lane < 64 ? lane : 0] = hs[lane < 64 ? lane : 0];
    if (lane < 11) hd[lane + 64] = hs[lane + 64];
  }
  __syncthreads();
  if (lane < LSEQ) {   // build padded x4 rows
    float2 a = *(float2*)(sX4 + lane * 6);
    float2 c = *(float2*)(sX4 + lane * 6 + 2);
    float2 d = *(float2*)(sX4 + lane * 6 + 4);
    *(float2*)(sX4P + lane * 8)     = a;
    *(float2*)(sX4P + lane * 8 + 2) = c;
    *(float2*)(sX4P + lane * 8 + 4) = d;
  }

  // ---- attn rows: sAT[l2][c] = tanh(attn_w @ xt[l2] + attn_b) ----
  if (lane < LSEQ) {
    float a[CHN];
    #pragma unroll
    for (int cc = 0; cc < CHN; ++cc) a[cc] = sXE[cc * LSEQ + lane];  // reshape view
    float o[CHN];
    #pragma unroll
    for (int c = 0; c < CHN; ++c) {
      float acc = attn_b[c];
      #pragma unroll
      for (int cc = 0; cc < CHN; ++cc) acc = fmaf(a[cc], attn_w[c * CHN + cc], acc);
      o[c] = ftanh(acc);
    }
    float4* ad = (float4*)(R1 + lane * CHN);
    ad[0] = make_float4(o[0],  o[1],  o[2],  o[3]);
    ad[1] = make_float4(o[4],  o[5],  o[6],  o[7]);
    ad[2] = make_float4(o[8],  o[9],  o[10], o[11]);
    ad[3] = make_float4(o[12], o[13], o[14], o[15]);
  }
  __syncthreads();

  // ---- convs fused with attn1 reduction -> x_cnn[48] ----
  {
    float* sAT = R1;
    const int o = lane & 15;
    const int seg = lane >> 4;
    const int L0 = (seg < 2) ? seg * 13 : 26 + (seg - 2) * 12;
    const int NL = (seg < 2) ? 13 : 12;
    int mcl[17];
    #pragma unroll
    for (int mm = 0; mm < 17; ++mm) {
      int m = L0 - 2 + mm;
      mcl[mm] = min(max(m, 0), LSEQ - 1);
    }
    float z1[13], z2[13], z3[13];
    #pragma unroll
    for (int u = 0; u < 13; ++u) { z1[u] = 0.0f; z2[u] = 0.0f; z3[u] = 0.0f; }
    for (int i = 0; i < CHN; ++i) {
      const float w1 = c1w[o * CHN + i];
      float w2a[3], w3a[5];
      #pragma unroll
      for (int t = 0; t < 3; ++t) w2a[t] = c2w[(o * CHN + i) * 3 + t];
      #pragma unroll
      for (int t = 0; t < 5; ++t) w3a[t] = c3w[(o * CHN + i) * 5 + t];
      const float* xrow = sXE + i * LSEQ;
      float xv[17];
      #pragma unroll
      for (int mm = 0; mm < 17; ++mm) {
        float v = xrow[mcl[mm]];
        if (mm < 2 || mm >= 14) {
          int m = L0 - 2 + mm;
          v = (m == mcl[mm]) ? v : 0.0f;
        }
        xv[mm] = v;
      }
      #pragma unroll
      for (int u = 0; u < 13; ++u) {
        z1[u] = fmaf(w1, xv[u + 2], z1[u]);
        z2[u] = fmaf(w2a[0], xv[u + 1], z2[u]);
        z2[u] = fmaf(w2a[1], xv[u + 2], z2[u]);
        z2[u] = fmaf(w2a[2], xv[u + 3], z2[u]);
        z3[u] = fmaf(w3a[0], xv[u],     z3[u]);
        z3[u] = fmaf(w3a[1], xv[u + 1], z3[u]);
        z3[u] = fmaf(w3a[2], xv[u + 2], z3[u]);
        z3[u] = fmaf(w3a[3], xv[u + 3], z3[u]);
        z3[u] = fmaf(w3a[4], xv[u + 4], z3[u]);
      }
    }
    const float b1v = c1b[o], b2v = c2b[o], b3v = c3b[o];
    float a1 = 0.0f, a2 = 0.0f, a3 = 0.0f;
    #pragma unroll
    for (int u = 0; u < 13; ++u) {
      if (u < NL) {
        int l = L0 + u;
        float v1 = lrelu(z1[u] + b1v);
        float v2 = lrelu(z2[u] + b2v);
        float v3 = lrelu(z3[u] + b3v);
        int f1 = o * LSEQ + l;
        int f2 = (CHN + o) * LSEQ + l;
        int f3 = (2 * CHN + o) * LSEQ + l;
        a1 += v1 * sAT[(f1 / 48) * CHN + ((f1 % 48) & 15)];
        a2 += v2 * sAT[(f2 / 48) * CHN + ((f2 % 48) & 15)];
        a3 += v3 * sAT[(f3 / 48) * CHN + ((f3 % 48) & 15)];
      }
    }
    a1 += __shfl_xor(a1, 16); a1 += __shfl_xor(a1, 32);
    a2 += __shfl_xor(a2, 16); a2 += __shfl_xor(a2, 32);
    a3 += __shfl_xor(a3, 16); a3 += __shfl_xor(a3, 32);
    if (lane < CHN) { sFE[o] = a1; sFE[CHN + o] = a2; sFE[2 * CHN + o] = a3; }
  }
  __syncthreads();

  // ---- 6a: T rows + column normalizers; sC[j] = {T[j][0..5], -, Zinv*x4[j][0..5]} ----
  float* sC = R1;
  if (lane < LSEQ) {
    float colj[HID];
    #pragma unroll
    for (int h = 0; h < HID; ++h) colj[h] = sX4[h * LSEQ + lane];  // reshape view
    *(float4*)(sC + lane * 16)     = make_float4(colj[0], colj[1], colj[2], colj[3]);
    *(float2*)(sC + lane * 16 + 4) = make_float2(colj[4], colj[5]);
    float zs = 0.0f;
    for (int i = 0; i < LSEQ; ++i) {
      const float4 r0 = *(const float4*)(sX4P + i * 8);
      const float2 r1 = *(const float2*)(sX4P + i * 8 + 4);
      float s = r0.x * colj[0];
      s = fmaf(r0.y, colj[1], s); s = fmaf(r0.z, colj[2], s);
      s = fmaf(r0.w, colj[3], s); s = fmaf(r1.x, colj[4], s);
      s = fmaf(r1.y, colj[5], s);
      zs += __expf(s * (1.0f / 6.0f));
    }
    const float zi = frcp(zs);
    const float4 q0 = *(const float4*)(sX4P + lane * 8);
    const float2 q1 = *(const float2*)(sX4P + lane * 8 + 4);
    *(float4*)(sC + lane * 16 + 8)  = make_float4(zi*q0.x, zi*q0.y, zi*q0.z, zi*q0.w);
    *(float2*)(sC + lane * 16 + 12) = make_float2(zi*q1.x, zi*q1.y);
  }
  __syncthreads();

  // ---- 6b: y0[i][h] = sum_j exp(s[i,j]/6) * WX[j][h] ----
  if (lane < LSEQ) {
    float rowi[HID];
    {
      const float4 q0 = *(const float4*)(sX4P + lane * 8);
      const float2 q1 = *(const float2*)(sX4P + lane * 8 + 4);
      rowi[0] = q0.x; rowi[1] = q0.y; rowi[2] = q0.z;
      rowi[3] = q0.w; rowi[4] = q1.x; rowi[5] = q1.y;
    }
    float ya[HID];
    #pragma unroll
    for (int h = 0; h < HID; ++h) ya[h] = 0.0f;
    for (int j = 0; j < LSEQ; ++j) {
      const float4 t0 = *(const float4*)(sC + j * 16);
      const float2 t1 = *(const float2*)(sC + j * 16 + 4);
      float s = rowi[0] * t0.x;
      s = fmaf(rowi[1], t0.y, s); s = fmaf(rowi[2], t0.z, s);
      s = fmaf(rowi[3], t0.w, s); s = fmaf(rowi[4], t1.x, s);
      s = fmaf(rowi[5], t1.y, s);
      const float e = __expf(s * (1.0f / 6.0f));
      const float4 w0 = *(const float4*)(sC + j * 16 + 8);
      const float2 w1 = *(const float2*)(sC + j * 16 + 12);
      ya[0] = fmaf(e, w0.x, ya[0]);
      ya[1] = fmaf(e, w0.y, ya[1]);
      ya[2] = fmaf(e, w0.z, ya[2]);
      ya[3] = fmaf(e, w0.w, ya[3]);
      ya[4] = fmaf(e, w1.x, ya[4]);
      ya[5] = fmaf(e, w1.y, ya[5]);
    }
    *(float2*)(sY + lane * 6)     = make_float2(ya[0], ya[1]);
    *(float2*)(sY + lane * 6 + 2) = make_float2(ya[2], ya[3]);
    *(float2*)(sY + lane * 6 + 4) = make_float2(ya[4], ya[5]);
  }
  __syncthreads();

  // ---- x_gru[g] = sum y0_flat[50g..50g+49]; then fc ----
  if (lane < HID) {
    float s = 0.0f;
    for (int m = 0; m < LSEQ; ++m) s += sY[lane * LSEQ + m];
    sFE[48 + lane] = s;
  }
  __syncthreads();
  if (lane < 2) {
    float acc = fc3b[lane];
    const float* wr = fc3w + lane * 54;
    #pragma unroll
    for (int k = 0; k < 54; ++k) acc = fmaf(wr[k], sFE[k], acc);
    out[(size_t)b * 2 + lane] = acc;
  }
}

// ---------------- Fallback: proven R2 monolith (used if ws_size too small) ----------------
constexpr int SLAB = 2560;
__global__ __launch_bounds__(256, 4) void fused_kernel(
    const float* __restrict__ x,
    const float* __restrict__ we_w, const float* __restrict__ we_b,
    const float* __restrict__ attn_w, const float* __restrict__ attn_b,
    const float* __restrict__ c1w, const float* __restrict__ c1b,
    const float* __restrict__ c2w, const float* __restrict__ c2b,
    const float* __restrict__ c3w, const float* __restrict__ c3b,
    const float* __restrict__ wih, const float* __restrict__ whh,
    const float* __restrict__ bih, const float* __restrict__ bhh,
    const float* __restrict__ fc3w, const float* __restrict__ fc3b,
    float* __restrict__ out)
{
  __shared__ __align__(16) float smem[4 * SLAB];
  const int tid  = threadIdx.x;
  const int wave = tid >> 6;
  const int lane = tid & 63;
  const int b    = blockIdx.x * 4 + wave;
  float* S    = smem + wave * SLAB;
  float* sXE  = S;
  float* sY   = S + 400;
  float* R1   = S + 800;
  float* sX4  = S + 1800;
  float* sX4P = S + 2104;
  float* sFE  = S + 2504;
  const float* xb = x + (size_t)b * (LSEQ * DIN);
  if (lane < LSEQ) {
    float xv[DIN];
    const float4* xr = (const float4*)(xb + lane * DIN);
    #pragma unroll
    for (int q = 0; q < 5; ++q) { float4 v = xr[q]; xv[4*q]=v.x; xv[4*q+1]=v.y; xv[4*q+2]=v.z; xv[4*q+3]=v.w; }
    float xe[CHN];
    #pragma unroll
    for (int c = 0; c < CHN; ++c) {
      float a = we_b[c];
      #pragma unroll
      for (int d = 0; d < DIN; ++d) a = fmaf(xv[d], we_w[c * DIN + d], a);
      xe[c] = a;
    }
    float4* xd = (float4*)(sXE + lane * CHN);
    xd[0] = make_float4(xe[0], xe[1], xe[2], xe[3]);
    xd[1] = make_float4(xe[4], xe[5], xe[6], xe[7]);
    xd[2] = make_float4(xe[8], xe[9], xe[10], xe[11]);
    xd[3] = make_float4(xe[12], xe[13], xe[14], xe[15]);
    float gi[18];
    #pragma unroll
    for (int g = 0; g < 18; ++g) {
      float a = bih[g];
      #pragma unroll
      for (int cc = 0; cc < CHN; ++cc) a = fmaf(xe[cc], wih[g * CHN + cc], a);
      gi[g] = a;
    }
    float4* gd = (float4*)(R1 + lane * 20);
    gd[0] = make_float4(gi[0], gi[1], gi[2], gi[3]);
    gd[1] = make_float4(gi[4], gi[5], gi[6], gi[7]);
    gd[2] = make_float4(gi[8], gi[9], gi[10], gi[11]);
    gd[3] = make_float4(gi[12], gi[13], gi[14], gi[15]);
    *(float2*)(R1 + lane * 20 + 16) = make_float2(gi[16], gi[17]);
  }
  __syncthreads();
  {
    const int g18 = (lane < 18) ? lane : 0;
    float wh[HID];
    #pragma unroll
    for (int k = 0; k < HID; ++k) wh[k] = whh[g18 * HID + k];
    const float bh = bhh[g18];
    const int m6 = lane % 6;
    float hh[HID];
    #pragma unroll
    for (int k = 0; k < HID; ++k) hh[k] = 0.0f;
    float hm = 0.0f;
    for (int l = 0; l < LSEQ; ++l) {
      float gh = bh;
      #pragma unroll
      for (int k = 0; k < HID; ++k) gh = fmaf(wh[k], hh[k], gh);
      float ghr = __shfl(gh, m6);
      float ghz = __shfl(gh, m6 + 6);
      float ghn = __shfl(gh, m6 + 12);
      const float* gl = R1 + l * 20;
      float r  = fsig(gl[m6] + ghr);
      float z  = fsig(gl[m6 + 6] + ghz);
      float n  = ftanh(gl[m6 + 12] + r * ghn);
      float hn = fmaf(z, hm - n, n);
      hm = hn;
      #pragma unroll
      for (int k = 0; k < HID; ++k) hh[k] = __shfl(hn, k);
      if (lane < HID) { sX4[l * HID + lane] = hn; sX4P[l * 8 + lane] = hn; }
    }
  }
  __syncthreads();
  if (lane < LSEQ) {
    float a[CHN];
    #pragma unroll
    for (int cc = 0; cc < CHN; ++cc) a[cc] = sXE[cc * LSEQ + lane];
    float o[CHN];
    #pragma unroll
    for (int c = 0; c < CHN; ++c) {
      float acc = attn_b[c];
      #pragma unroll
      for (int cc = 0; cc < CHN; ++cc) acc = fmaf(a[cc], attn_w[c * CHN + cc], acc);
      o[c] = ftanh(acc);
    }
    float4* ad = (float4*)(R1 + lane * CHN);
    ad[0] = make_float4(o[0], o[1], o[2], o[3]);
    ad[1] = make_float4(o[4], o[5], o[6], o[7]);
    ad[2] = make_float4(o[8], o[9], o[10], o[11]);
    ad[3] = make_float4(o[12], o[13], o[14], o[15]);
  }
  __syncthreads();
  {
    float* sAT = R1;
    const int o = lane & 15;
    const int seg = lane >> 4;
    const int L0 = (seg < 2) ? seg * 13 : 26 + (seg - 2) * 12;
    const int NL = (seg < 2) ? 13 : 12;
    int mcl[17];
    #pragma unroll
    for (int mm = 0; mm < 17; ++mm) { int m = L0 - 2 + mm; mcl[mm] = min(max(m, 0), LSEQ - 1); }
    float z1[13], z2[13], z3[13];
    #pragma unroll
    for (int u = 0; u < 13; ++u) { z1[u] = 0.0f; z2[u] = 0.0f; z3[u] = 0.0f; }
    for (int i = 0; i < CHN; ++i) {
      const float w1 = c1w[o * CHN + i];
      float w2a[3], w3a[5];
      #pragma unroll
      for (int t = 0; t < 3; ++t) w2a[t] = c2w[(o * CHN + i) * 3 + t];
      #pragma unroll
      for (int t = 0; t < 5; ++t) w3a[t] = c3w[(o * CHN + i) * 5 + t];
      const float* xrow = sXE + i * LSEQ;
      float xv[17];
      #pragma unroll
      for (int mm = 0; mm < 17; ++mm) {
        float v = xrow[mcl[mm]];
        if (mm < 2 || mm >= 14) { int m = L0 - 2 + mm; v = (m == mcl[mm]) ? v : 0.0f; }
        xv[mm] = v;
      }
      #pragma unroll
      for (int u = 0; u < 13; ++u) {
        z1[u] = fmaf(w1, xv[u + 2], z1[u]);
        z2[u] = fmaf(w2a[0], xv[u + 1], z2[u]);
        z2[u] = fmaf(w2a[1], xv[u + 2], z2[u]);
        z2[u] = fmaf(w2a[2], xv[u + 3], z2[u]);
        z3[u] = fmaf(w3a[0], xv[u],     z3[u]);
        z3[u] = fmaf(w3a[1], xv[u + 1], z3[u]);
        z3[u] = fmaf(w3a[2], xv[u + 2], z3[u]);
        z3[u] = fmaf(w3a[3], xv[u + 3], z3[u]);
        z3[u] = fmaf(w3a[4], xv[u + 4], z3[u]);
      }
    }
    const float b1v = c1b[o], b2v = c2b[o], b3v = c3b[o];
    float a1 = 0.0f, a2 = 0.0f, a3 = 0.0f;
    #pragma unroll
    for (int u = 0; u < 13; ++u) {
      if (u < NL) {
        int l = L0 + u;
        float v1 = lrelu(z1[u] + b1v);
        float v2 = lrelu(z2[u] + b2v);
        float v3 = lrelu(z3[u] + b3v);
        int f1 = o * LSEQ + l;
        int f2 = (CHN + o) * LSEQ + l;
        int f3 = (2 * CHN + o) * LSEQ + l;
        a1 += v1 * sAT[(f1 / 48) * CHN + ((f1 % 48) & 15)];
        a2 += v2 * sAT[(f2 / 48) * CHN + ((f2 % 48) & 15)];
        a3 += v3 * sAT[(f3 / 48) * CHN + ((f3 % 48) & 15)];
      }
    }
    a1 += __shfl_xor(a1, 16); a1 += __shfl_xor(a1, 32);
    a2 += __shfl_xor(a2, 16); a2 += __shfl_xor(a2, 32);
    a3 += __shfl_xor(a3, 16); a3 += __shfl_xor(a3, 32);
    if (lane < CHN) { sFE[o] = a1; sFE[CHN + o] = a2; sFE[2 * CHN + o] = a3; }
  }
  __syncthreads();
  float* sC = R1;
  if (lane < LSEQ) {
    float colj[HID];
    #pragma unroll
    for (int h = 0; h < HID; ++h) colj[h] = sX4[h * LSEQ + lane];
    *(float4*)(sC + lane * 16)     = make_float4(colj[0], colj[1], colj[2], colj[3]);
    *(float2*)(sC + lane * 16 + 4) = make_float2(colj[4], colj[5]);
    float zs = 0.0f;
    for (int i = 0; i < LSEQ; ++i) {
      const float4 r0 = *(const float4*)(sX4P + i * 8);
      const float2 r1 = *(const float2*)(sX4P + i * 8 + 4);
      float s = r0.x * colj[0];
      s = fmaf(r0.y, colj[1], s); s = fmaf(r0.z, colj[2], s);
      s = fmaf(r0.w, colj[3], s); s = fmaf(r1.x, colj[4], s);
      s = fmaf(r1.y, colj[5], s);
      zs += __expf(s * (1.0f / 6.0f));
    }
    const float zi = frcp(zs);
    const float4 q0 = *(const float4*)(sX4P + lane * 8);
    const float2 q1 = *(const float2*)(sX4P + lane * 8 + 4);
    *(float4*)(sC + lane * 16 + 8)  = make_float4(zi*q0.x, zi*q0.y, zi*q0.z, zi*q0.w);
    *(float2*)(sC + lane * 16 + 12) = make_float2(zi*q1.x, zi*q1.y);
  }
  __syncthreads();
  if (lane < LSEQ) {
    float rowi[HID];
    {
      const float4 q0 = *(const float4*)(sX4P + lane * 8);
      const float2 q1 = *(const float2*)(sX4P + lane * 8 + 4);
      rowi[0] = q0.x; rowi[1] = q0.y; rowi[2] = q0.z;
      rowi[3] = q0.w; rowi[4] = q1.x; rowi[5] = q1.y;
    }
    float ya[HID];
    #pragma unroll
    for (int h = 0; h < HID; ++h) ya[h] = 0.0f;
    for (int j = 0; j < LSEQ; ++j) {
      const float4 t0 = *(const float4*)(sC + j * 16);
      const float2 t1 = *(const float2*)(sC + j * 16 + 4);
      float s = rowi[0] * t0.x;
      s = fmaf(rowi[1], t0.y, s); s = fmaf(rowi[2], t0.z, s);
      s = fmaf(rowi[3], t0.w, s); s = fmaf(rowi[4], t1.x, s);
      s = fmaf(rowi[5], t1.y, s);
      const float e = __expf(s * (1.0f / 6.0f));
      const float4 w0 = *(const float4*)(sC + j * 16 + 8);
      const float2 w1 = *(const float2*)(sC + j * 16 + 12);
      ya[0] = fmaf(e, w0.x, ya[0]);
      ya[1] = fmaf(e, w0.y, ya[1]);
      ya[2] = fmaf(e, w0.z, ya[2]);
      ya[3] = fmaf(e, w0.w, ya[3]);
      ya[4] = fmaf(e, w1.x, ya[4]);
      ya[5] = fmaf(e, w1.y, ya[5]);
    }
    *(float2*)(sY + lane * 6)     = make_float2(ya[0], ya[1]);
    *(float2*)(sY + lane * 6 + 2) = make_float2(ya[2], ya[3]);
    *(float2*)(sY + lane * 6 + 4) = make_float2(ya[4], ya[5]);
  }
  __syncthreads();
  if (lane < HID) {
    float s = 0.0f;
    for (int m = 0; m < LSEQ; ++m) s += sY[lane * LSEQ + m];
    sFE[48 + lane] = s;
  }
  __syncthreads();
  if (lane < 2) {
    float acc = fc3b[lane];
    const float* wr = fc3w + lane * 54;
    #pragma unroll
    for (int k = 0; k < 54; ++k) acc = fmaf(wr[k], sFE[k], acc);
    out[(size_t)b * 2 + lane] = acc;
  }
}

extern "C" void kernel_launch(void* const* d_in, const int* in_sizes, int n_in,
                              void* d_out, int out_size, void* d_ws, size_t ws_size,
                              hipStream_t stream) {
  (void)in_sizes; (void)n_in; (void)out_size;
  const float* x      = (const float*)d_in[0];
  const float* we_w   = (const float*)d_in[1];
  const float* we_b   = (const float*)d_in[2];
  const float* attn_w = (const float*)d_in[3];
  const float* attn_b = (const float*)d_in[4];
  const float* c1w    = (const float*)d_in[5];
  const float* c1b    = (const float*)d_in[6];
  const float* c2w    = (const float*)d_in[7];
  const float* c2b    = (const float*)d_in[8];
  const float* c3w    = (const float*)d_in[9];
  const float* c3b    = (const float*)d_in[10];
  const float* wih    = (const float*)d_in[11];
  const float* whh    = (const float*)d_in[12];
  const float* bih    = (const float*)d_in[13];
  const float* bhh    = (const float*)d_in[14];
  const float* fc3w   = (const float*)d_in[15];
  const float* fc3b   = (const float*)d_in[16];
  float* out = (float*)d_out;

  const size_t xe_elems = (size_t)BATCH * 800;   // 52.4 MB
  const size_t gi_elems = (size_t)BATCH * 1000;  // 65.5 MB
  const size_t x4_elems = (size_t)BATCH * 300;   // 19.7 MB
  const size_t need = (xe_elems + gi_elems + x4_elems) * sizeof(float);

  if (ws_size >= need) {
    float* xeg = (float*)d_ws;
    float* gig = xeg + xe_elems;
    float* x4g = gig + gi_elems;
    k_embed<<<(BATCH * LSEQ) / 256, 256, 0, stream>>>(x, we_w, we_b, wih, bih, xeg, gig);
    k_gru<<<BATCH / 64, 64, 0, stream>>>(gig, whh, bhh, x4g);
    k_tail<<<BATCH / 4, 256, 0, stream>>>(xeg, x4g, attn_w, attn_b,
                                          c1w, c1b, c2w, c2b, c3w, c3b,
                                          fc3w, fc3b, out);
  } else {
    fused_kernel<<<BATCH / 4, 256, 0, stream>>>(
        x, we_w, we_b, attn_w, attn_b, c1w, c1b, c2w, c2b, c3w, c3b,
        wih, whh, bih, bhh, fc3w, fc3b, out);
  }
}

// Round 4
// 337.273 us; speedup vs baseline: 1.0258x; 1.0258x over previous
//
#include <hip/hip_runtime.h>

#define BATCH 16384
#define LSEQ  50
#define DIN   20
#define CHN   16
#define HID   6

__device__ __forceinline__ float frcp(float x){ return __builtin_amdgcn_rcpf(x); }
__device__ __forceinline__ float fsig(float x){ return frcp(1.0f + __expf(-x)); }
__device__ __forceinline__ float ftanh(float x){ float t = __expf(2.0f*x); return (t - 1.0f) * frcp(t + 1.0f); }
__device__ __forceinline__ float lrelu(float v){ return v > 0.0f ? v : 0.1f*v; }

// ---------------- K1: gi[18] per (b,l) row; full 80B rows (2 zero floats pad -> full-line stores) ----
__global__ __launch_bounds__(256) void k_embed(
    const float* __restrict__ x,
    const float* __restrict__ we_w, const float* __restrict__ we_b,
    const float* __restrict__ wih,  const float* __restrict__ bih,
    float* __restrict__ gig)
{
  const size_t r = (size_t)blockIdx.x * 256 + threadIdx.x;   // [0, B*L)
  float xv[DIN];
  const float4* xr = (const float4*)(x + r * DIN);
  #pragma unroll
  for (int q = 0; q < 5; ++q) {
    float4 v = xr[q];
    xv[4*q] = v.x; xv[4*q+1] = v.y; xv[4*q+2] = v.z; xv[4*q+3] = v.w;
  }
  float xe[CHN];
  #pragma unroll
  for (int c = 0; c < CHN; ++c) {
    float a = we_b[c];
    #pragma unroll
    for (int d = 0; d < DIN; ++d) a = fmaf(xv[d], we_w[c * DIN + d], a);
    xe[c] = a;
  }
  float gi[18];
  #pragma unroll
  for (int g = 0; g < 18; ++g) {
    float a = bih[g];
    #pragma unroll
    for (int c = 0; c < CHN; ++c) a = fmaf(xe[c], wih[g * CHN + c], a);
    gi[g] = a;
  }
  float4* go = (float4*)(gig + r * 20);
  go[0] = make_float4(gi[0],  gi[1],  gi[2],  gi[3]);
  go[1] = make_float4(gi[4],  gi[5],  gi[6],  gi[7]);
  go[2] = make_float4(gi[8],  gi[9],  gi[10], gi[11]);
  go[3] = make_float4(gi[12], gi[13], gi[14], gi[15]);
  go[4] = make_float4(gi[16], gi[17], 0.0f, 0.0f);
}

// ---------------- K2: GRU, one element per lane; unroll-2, prefetch depth 2 ----------------
__global__ __launch_bounds__(64) void k_gru(
    const float* __restrict__ gig,
    const float* __restrict__ whh, const float* __restrict__ bhh,
    float* __restrict__ x4g)
{
  const int b = blockIdx.x * 64 + threadIdx.x;
  float wh[18][HID];
  #pragma unroll
  for (int g = 0; g < 18; ++g)
    #pragma unroll
    for (int k = 0; k < HID; ++k) wh[g][k] = whh[g * HID + k];
  float bh[18];
  #pragma unroll
  for (int g = 0; g < 18; ++g) bh[g] = bhh[g];

  const float* gp = gig + (size_t)b * (LSEQ * 20);
  float* op = x4g + (size_t)b * (LSEQ * HID);

  float hh[HID];
  #pragma unroll
  for (int k = 0; k < HID; ++k) hh[k] = 0.0f;

  float4 A0, A1, A2, A3, A4, B0, B1, B2, B3, B4;
  {
    const float4* q = (const float4*)gp;
    A0 = q[0]; A1 = q[1]; A2 = q[2]; A3 = q[3]; A4 = q[4];
    const float4* q2 = (const float4*)(gp + 20);
    B0 = q2[0]; B1 = q2[1]; B2 = q2[2]; B3 = q2[3]; B4 = q2[4];
  }

  auto gstep = [&](const float4 R0, const float4 R1, const float4 R2,
                   const float4 R3, const float4 R4, float* OP) {
    float gh[18];
    #pragma unroll
    for (int g = 0; g < 18; ++g) {
      float a = bh[g];
      #pragma unroll
      for (int k = 0; k < HID; ++k) a = fmaf(wh[g][k], hh[k], a);
      gh[g] = a;
    }
    float r0 = fsig(R0.x + gh[0]),  r1 = fsig(R0.y + gh[1]);
    float r2 = fsig(R0.z + gh[2]),  r3 = fsig(R0.w + gh[3]);
    float r4 = fsig(R1.x + gh[4]),  r5 = fsig(R1.y + gh[5]);
    float z0 = fsig(R1.z + gh[6]),  z1 = fsig(R1.w + gh[7]);
    float z2 = fsig(R2.x + gh[8]),  z3 = fsig(R2.y + gh[9]);
    float z4 = fsig(R2.z + gh[10]), z5 = fsig(R2.w + gh[11]);
    float n0 = ftanh(fmaf(r0, gh[12], R3.x));
    float n1 = ftanh(fmaf(r1, gh[13], R3.y));
    float n2 = ftanh(fmaf(r2, gh[14], R3.z));
    float n3 = ftanh(fmaf(r3, gh[15], R3.w));
    float n4 = ftanh(fmaf(r4, gh[16], R4.x));
    float n5 = ftanh(fmaf(r5, gh[17], R4.y));
    hh[0] = fmaf(z0, hh[0] - n0, n0);
    hh[1] = fmaf(z1, hh[1] - n1, n1);
    hh[2] = fmaf(z2, hh[2] - n2, n2);
    hh[3] = fmaf(z3, hh[3] - n3, n3);
    hh[4] = fmaf(z4, hh[4] - n4, n4);
    hh[5] = fmaf(z5, hh[5] - n5, n5);
    *(float2*)(OP)     = make_float2(hh[0], hh[1]);
    *(float2*)(OP + 2) = make_float2(hh[2], hh[3]);
    *(float2*)(OP + 4) = make_float2(hh[4], hh[5]);
  };

  for (int l = 0; l < LSEQ; l += 2) {
    gstep(A0, A1, A2, A3, A4, op + l * HID);
    if (l + 2 < LSEQ) {
      const float4* q = (const float4*)(gp + (l + 2) * 20);
      A0 = q[0]; A1 = q[1]; A2 = q[2]; A3 = q[3]; A4 = q[4];
    }
    gstep(B0, B1, B2, B3, B4, op + (l + 1) * HID);
    if (l + 3 < LSEQ) {
      const float4* q = (const float4*)(gp + (l + 3) * 20);
      B0 = q[0]; B1 = q[1]; B2 = q[2]; B3 = q[3]; B4 = q[4];
    }
  }
}

// ---------------- K3: per-element wave — xe recompute, attn, convs (padded rows), softmax, fc ----
// Per-wave LDS slab (floats), SLAB3 = 2464 -> 9856 B/wave, 39424 B/block -> 4 blocks/CU.
//  [0,896)     sXEp: padded reshape rows [16][56]; P[i][2+m] = xe_flat[i*50+m], zero edges.
//              After conv phase: sY aliases [0,300).
//  [896,1696)  R1  : sAT [50][16] -> sC [50][16] rows {T[0..5], -, WX[8..13]}
//  [1696,2000) sX4 : x4 flat (l*6+h)
//  [2000,2400) sX4P: x4 padded [50][8]
//  [2400,2454) sFE : feat[54]
constexpr int SLAB3 = 2464;

__global__ __launch_bounds__(256, 4) void k_tail(
    const float* __restrict__ x, const float* __restrict__ x4g,
    const float* __restrict__ we_w, const float* __restrict__ we_b,
    const float* __restrict__ attn_w, const float* __restrict__ attn_b,
    const float* __restrict__ c1w, const float* __restrict__ c1b,
    const float* __restrict__ c2w, const float* __restrict__ c2b,
    const float* __restrict__ c3w, const float* __restrict__ c3b,
    const float* __restrict__ fc3w, const float* __restrict__ fc3b,
    float* __restrict__ out)
{
  __shared__ __align__(16) float smem[4 * SLAB3];
  const int tid  = threadIdx.x;
  const int wave = tid >> 6;
  const int lane = tid & 63;
  const int b    = blockIdx.x * 4 + wave;

  float* S    = smem + wave * SLAB3;
  float* sXEp = S;
  float* sY   = S;          // alias, live after conv phase
  float* R1   = S + 896;
  float* sX4  = S + 1696;
  float* sX4P = S + 2000;
  float* sFE  = S + 2400;

  // ---- zero pad edges of conv rows ----
  if (lane < CHN) {
    *(float2*)(sXEp + lane * 56)      = make_float2(0.0f, 0.0f);
    *(float4*)(sXEp + lane * 56 + 52) = make_float4(0.0f, 0.0f, 0.0f, 0.0f);
  }

  // ---- stage x4 (75 f4) ----
  {
    const float4* hs = (const float4*)(x4g + (size_t)b * 300);
    float4* hd = (float4*)sX4;
    hd[lane] = hs[lane];
    if (lane < 11) hd[64 + lane] = hs[64 + lane];
  }

  // ---- recompute xe from x; scatter into padded reshape rows ----
  if (lane < LSEQ) {
    float xv[DIN];
    const float4* xr = (const float4*)(x + ((size_t)b * LSEQ + lane) * DIN);
    #pragma unroll
    for (int q = 0; q < 5; ++q) {
      float4 v = xr[q];
      xv[4*q] = v.x; xv[4*q+1] = v.y; xv[4*q+2] = v.z; xv[4*q+3] = v.w;
    }
    const int k0 = lane * CHN;
    #pragma unroll
    for (int c = 0; c < CHN; ++c) {
      float a = we_b[c];
      #pragma unroll
      for (int d = 0; d < DIN; ++d) a = fmaf(xv[d], we_w[c * DIN + d], a);
      int kk = k0 + c;
      int i  = kk / 50;
      int m  = kk - i * 50;
      sXEp[i * 56 + 2 + m] = a;      // P[i][2+m] = xe_flat[kk]
    }
  }
  __syncthreads();

  // ---- build padded x4 rows ----
  if (lane < LSEQ) {
    float2 a = *(float2*)(sX4 + lane * 6);
    float2 c = *(float2*)(sX4 + lane * 6 + 2);
    float2 d = *(float2*)(sX4 + lane * 6 + 4);
    *(float2*)(sX4P + lane * 8)     = a;
    *(float2*)(sX4P + lane * 8 + 2) = c;
    *(float2*)(sX4P + lane * 8 + 4) = d;
  }

  // ---- attn rows: sAT[l2][c] = tanh(attn_w @ xt[l2] + attn_b) ----
  if (lane < LSEQ) {
    float a[CHN];
    #pragma unroll
    for (int cc = 0; cc < CHN; ++cc) a[cc] = sXEp[cc * 56 + 2 + lane];  // xt[l2][cc]
    float o[CHN];
    #pragma unroll
    for (int c = 0; c < CHN; ++c) {
      float acc = attn_b[c];
      #pragma unroll
      for (int cc = 0; cc < CHN; ++cc) acc = fmaf(a[cc], attn_w[c * CHN + cc], acc);
      o[c] = ftanh(acc);
    }
    float4* ad = (float4*)(R1 + lane * CHN);
    ad[0] = make_float4(o[0],  o[1],  o[2],  o[3]);
    ad[1] = make_float4(o[4],  o[5],  o[6],  o[7]);
    ad[2] = make_float4(o[8],  o[9],  o[10], o[11]);
    ad[3] = make_float4(o[12], o[13], o[14], o[15]);
  }
  __syncthreads();

  // ---- convs (vector LDS loads from padded rows) fused with attn1 reduction ----
  {
    float* sAT = R1;
    const int o   = lane & 15;
    const int seg = lane >> 4;
    const int s   = seg * 12;               // 0,12,24,36 (each mult of 4 -> aligned b128)
    const int NL  = (seg == 3) ? 14 : 12;
    float z1[14], z2[14], z3[14];
    #pragma unroll
    for (int u = 0; u < 14; ++u) { z1[u] = 0.0f; z2[u] = 0.0f; z3[u] = 0.0f; }
    for (int i = 0; i < CHN; ++i) {
      const float w1 = c1w[o * CHN + i];
      float w2a[3], w3a[5];
      #pragma unroll
      for (int t = 0; t < 3; ++t) w2a[t] = c2w[(o * CHN + i) * 3 + t];
      #pragma unroll
      for (int t = 0; t < 5; ++t) w3a[t] = c3w[(o * CHN + i) * 5 + t];
      const float4* wp = (const float4*)(sXEp + i * 56 + s);
      float4 q0 = wp[0], q1 = wp[1], q2 = wp[2], q3 = wp[3], q4 = wp[4];
      float xv[20] = {q0.x,q0.y,q0.z,q0.w, q1.x,q1.y,q1.z,q1.w,
                      q2.x,q2.y,q2.z,q2.w, q3.x,q3.y,q3.z,q3.w,
                      q4.x,q4.y,q4.z,q4.w};
      // output l = s+u uses P[l..l+4] = xv[u..u+4]
      #pragma unroll
      for (int u = 0; u < 14; ++u) {
        z1[u] = fmaf(w1, xv[u + 2], z1[u]);
        z2[u] = fmaf(w2a[0], xv[u + 1], z2[u]);
        z2[u] = fmaf(w2a[1], xv[u + 2], z2[u]);
        z2[u] = fmaf(w2a[2], xv[u + 3], z2[u]);
        z3[u] = fmaf(w3a[0], xv[u],     z3[u]);
        z3[u] = fmaf(w3a[1], xv[u + 1], z3[u]);
        z3[u] = fmaf(w3a[2], xv[u + 2], z3[u]);
        z3[u] = fmaf(w3a[3], xv[u + 3], z3[u]);
        z3[u] = fmaf(w3a[4], xv[u + 4], z3[u]);
      }
    }
    const float b1v = c1b[o], b2v = c2b[o], b3v = c3b[o];
    float a1 = 0.0f, a2 = 0.0f, a3 = 0.0f;
    #pragma unroll
    for (int u = 0; u < 14; ++u) {
      if (u < NL) {
        int l = s + u;
        float v1 = lrelu(z1[u] + b1v);
        float v2 = lrelu(z2[u] + b2v);
        float v3 = lrelu(z3[u] + b3v);
        int f1 = o * LSEQ + l;
        int f2 = (CHN + o) * LSEQ + l;
        int f3 = (2 * CHN + o) * LSEQ + l;
        a1 += v1 * sAT[(f1 / 48) * CHN + ((f1 % 48) & 15)];
        a2 += v2 * sAT[(f2 / 48) * CHN + ((f2 % 48) & 15)];
        a3 += v3 * sAT[(f3 / 48) * CHN + ((f3 % 48) & 15)];
      }
    }
    a1 += __shfl_xor(a1, 16); a1 += __shfl_xor(a1, 32);
    a2 += __shfl_xor(a2, 16); a2 += __shfl_xor(a2, 32);
    a3 += __shfl_xor(a3, 16); a3 += __shfl_xor(a3, 32);
    if (lane < CHN) { sFE[o] = a1; sFE[CHN + o] = a2; sFE[2 * CHN + o] = a3; }
  }
  __syncthreads();

  // ---- 6a: T rows + column normalizers; sC[j] = {T[j][0..5], -, Zinv*x4[j][0..5]} ----
  float* sC = R1;
  if (lane < LSEQ) {
    float colj[HID];
    #pragma unroll
    for (int h = 0; h < HID; ++h) colj[h] = sX4[h * LSEQ + lane];  // reshape view
    *(float4*)(sC + lane * 16)     = make_float4(colj[0], colj[1], colj[2], colj[3]);
    *(float2*)(sC + lane * 16 + 4) = make_float2(colj[4], colj[5]);
    float zs = 0.0f;
    for (int i = 0; i < LSEQ; ++i) {
      const float4 r0 = *(const float4*)(sX4P + i * 8);
      const float2 r1 = *(const float2*)(sX4P + i * 8 + 4);
      float s = r0.x * colj[0];
      s = fmaf(r0.y, colj[1], s); s = fmaf(r0.z, colj[2], s);
      s = fmaf(r0.w, colj[3], s); s = fmaf(r1.x, colj[4], s);
      s = fmaf(r1.y, colj[5], s);
      zs += __expf(s * (1.0f / 6.0f));
    }
    const float zi = frcp(zs);
    const float4 q0 = *(const float4*)(sX4P + lane * 8);
    const float2 q1 = *(const float2*)(sX4P + lane * 8 + 4);
    *(float4*)(sC + lane * 16 + 8)  = make_float4(zi*q0.x, zi*q0.y, zi*q0.z, zi*q0.w);
    *(float2*)(sC + lane * 16 + 12) = make_float2(zi*q1.x, zi*q1.y);
  }
  __syncthreads();

  // ---- 6b: y0[i][h] = sum_j exp(s[i,j]/6) * WX[j][h] ----
  if (lane < LSEQ) {
    float rowi[HID];
    {
      const float4 q0 = *(const float4*)(sX4P + lane * 8);
      const float2 q1 = *(const float2*)(sX4P + lane * 8 + 4);
      rowi[0] = q0.x; rowi[1] = q0.y; rowi[2] = q0.z;
      rowi[3] = q0.w; rowi[4] = q1.x; rowi[5] = q1.y;
    }
    float ya[HID];
    #pragma unroll
    for (int h = 0; h < HID; ++h) ya[h] = 0.0f;
    for (int j = 0; j < LSEQ; ++j) {
      const float4 t0 = *(const float4*)(sC + j * 16);
      const float2 t1 = *(const float2*)(sC + j * 16 + 4);
      float s = rowi[0] * t0.x;
      s = fmaf(rowi[1], t0.y, s); s = fmaf(rowi[2], t0.z, s);
      s = fmaf(rowi[3], t0.w, s); s = fmaf(rowi[4], t1.x, s);
      s = fmaf(rowi[5], t1.y, s);
      const float e = __expf(s * (1.0f / 6.0f));
      const float4 w0 = *(const float4*)(sC + j * 16 + 8);
      const float2 w1 = *(const float2*)(sC + j * 16 + 12);
      ya[0] = fmaf(e, w0.x, ya[0]);
      ya[1] = fmaf(e, w0.y, ya[1]);
      ya[2] = fmaf(e, w0.z, ya[2]);
      ya[3] = fmaf(e, w0.w, ya[3]);
      ya[4] = fmaf(e, w1.x, ya[4]);
      ya[5] = fmaf(e, w1.y, ya[5]);
    }
    *(float2*)(sY + lane * 6)     = make_float2(ya[0], ya[1]);
    *(float2*)(sY + lane * 6 + 2) = make_float2(ya[2], ya[3]);
    *(float2*)(sY + lane * 6 + 4) = make_float2(ya[4], ya[5]);
  }
  __syncthreads();

  // ---- x_gru + fc ----
  if (lane < HID) {
    float s = 0.0f;
    for (int m = 0; m < LSEQ; ++m) s += sY[lane * LSEQ + m];
    sFE[48 + lane] = s;
  }
  __syncthreads();
  if (lane < 2) {
    float acc = fc3b[lane];
    const float* wr = fc3w + lane * 54;
    #pragma unroll
    for (int k = 0; k < 54; ++k) acc = fmaf(wr[k], sFE[k], acc);
    out[(size_t)b * 2 + lane] = acc;
  }
}

// ---------------- Fallback: proven R2 monolith (used if ws_size too small) ----------------
constexpr int SLAB = 2560;
__global__ __launch_bounds__(256, 4) void fused_kernel(
    const float* __restrict__ x,
    const float* __restrict__ we_w, const float* __restrict__ we_b,
    const float* __restrict__ attn_w, const float* __restrict__ attn_b,
    const float* __restrict__ c1w, const float* __restrict__ c1b,
    const float* __restrict__ c2w, const float* __restrict__ c2b,
    const float* __restrict__ c3w, const float* __restrict__ c3b,
    const float* __restrict__ wih, const float* __restrict__ whh,
    const float* __restrict__ bih, const float* __restrict__ bhh,
    const float* __restrict__ fc3w, const float* __restrict__ fc3b,
    float* __restrict__ out)
{
  __shared__ __align__(16) float smem[4 * SLAB];
  const int tid  = threadIdx.x;
  const int wave = tid >> 6;
  const int lane = tid & 63;
  const int b    = blockIdx.x * 4 + wave;
  float* S    = smem + wave * SLAB;
  float* sXE  = S;
  float* sY   = S + 400;
  float* R1   = S + 800;
  float* sX4  = S + 1800;
  float* sX4P = S + 2104;
  float* sFE  = S + 2504;
  const float* xb = x + (size_t)b * (LSEQ * DIN);
  if (lane < LSEQ) {
    float xv[DIN];
    const float4* xr = (const float4*)(xb + lane * DIN);
    #pragma unroll
    for (int q = 0; q < 5; ++q) { float4 v = xr[q]; xv[4*q]=v.x; xv[4*q+1]=v.y; xv[4*q+2]=v.z; xv[4*q+3]=v.w; }
    float xe[CHN];
    #pragma unroll
    for (int c = 0; c < CHN; ++c) {
      float a = we_b[c];
      #pragma unroll
      for (int d = 0; d < DIN; ++d) a = fmaf(xv[d], we_w[c * DIN + d], a);
      xe[c] = a;
    }
    float4* xd = (float4*)(sXE + lane * CHN);
    xd[0] = make_float4(xe[0], xe[1], xe[2], xe[3]);
    xd[1] = make_float4(xe[4], xe[5], xe[6], xe[7]);
    xd[2] = make_float4(xe[8], xe[9], xe[10], xe[11]);
    xd[3] = make_float4(xe[12], xe[13], xe[14], xe[15]);
    float gi[18];
    #pragma unroll
    for (int g = 0; g < 18; ++g) {
      float a = bih[g];
      #pragma unroll
      for (int cc = 0; cc < CHN; ++cc) a = fmaf(xe[cc], wih[g * CHN + cc], a);
      gi[g] = a;
    }
    float4* gd = (float4*)(R1 + lane * 20);
    gd[0] = make_float4(gi[0], gi[1], gi[2], gi[3]);
    gd[1] = make_float4(gi[4], gi[5], gi[6], gi[7]);
    gd[2] = make_float4(gi[8], gi[9], gi[10], gi[11]);
    gd[3] = make_float4(gi[12], gi[13], gi[14], gi[15]);
    *(float2*)(R1 + lane * 20 + 16) = make_float2(gi[16], gi[17]);
  }
  __syncthreads();
  {
    const int g18 = (lane < 18) ? lane : 0;
    float wh[HID];
    #pragma unroll
    for (int k = 0; k < HID; ++k) wh[k] = whh[g18 * HID + k];
    const float bh = bhh[g18];
    const int m6 = lane % 6;
    float hh[HID];
    #pragma unroll
    for (int k = 0; k < HID; ++k) hh[k] = 0.0f;
    float hm = 0.0f;
    for (int l = 0; l < LSEQ; ++l) {
      float gh = bh;
      #pragma unroll
      for (int k = 0; k < HID; ++k) gh = fmaf(wh[k], hh[k], gh);
      float ghr = __shfl(gh, m6);
      float ghz = __shfl(gh, m6 + 6);
      float ghn = __shfl(gh, m6 + 12);
      const float* gl = R1 + l * 20;
      float r  = fsig(gl[m6] + ghr);
      float z  = fsig(gl[m6 + 6] + ghz);
      float n  = ftanh(gl[m6 + 12] + r * ghn);
      float hn = fmaf(z, hm - n, n);
      hm = hn;
      #pragma unroll
      for (int k = 0; k < HID; ++k) hh[k] = __shfl(hn, k);
      if (lane < HID) { sX4[l * HID + lane] = hn; sX4P[l * 8 + lane] = hn; }
    }
  }
  __syncthreads();
  if (lane < LSEQ) {
    float a[CHN];
    #pragma unroll
    for (int cc = 0; cc < CHN; ++cc) a[cc] = sXE[cc * LSEQ + lane];
    float o[CHN];
    #pragma unroll
    for (int c = 0; c < CHN; ++c) {
      float acc = attn_b[c];
      #pragma unroll
      for (int cc = 0; cc < CHN; ++cc) acc = fmaf(a[cc], attn_w[c * CHN + cc], acc);
      o[c] = ftanh(acc);
    }
    float4* ad = (float4*)(R1 + lane * CHN);
    ad[0] = make_float4(o[0], o[1], o[2], o[3]);
    ad[1] = make_float4(o[4], o[5], o[6], o[7]);
    ad[2] = make_float4(o[8], o[9], o[10], o[11]);
    ad[3] = make_float4(o[12], o[13], o[14], o[15]);
  }
  __syncthreads();
  {
    float* sAT = R1;
    const int o = lane & 15;
    const int seg = lane >> 4;
    const int L0 = (seg < 2) ? seg * 13 : 26 + (seg - 2) * 12;
    const int NL = (seg < 2) ? 13 : 12;
    int mcl[17];
    #pragma unroll
    for (int mm = 0; mm < 17; ++mm) { int m = L0 - 2 + mm; mcl[mm] = min(max(m, 0), LSEQ - 1); }
    float z1[13], z2[13], z3[13];
    #pragma unroll
    for (int u = 0; u < 13; ++u) { z1[u] = 0.0f; z2[u] = 0.0f; z3[u] = 0.0f; }
    for (int i = 0; i < CHN; ++i) {
      const float w1 = c1w[o * CHN + i];
      float w2a[3], w3a[5];
      #pragma unroll
      for (int t = 0; t < 3; ++t) w2a[t] = c2w[(o * CHN + i) * 3 + t];
      #pragma unroll
      for (int t = 0; t < 5; ++t) w3a[t] = c3w[(o * CHN + i) * 5 + t];
      const float* xrow = sXE + i * LSEQ;
      float xv[17];
      #pragma unroll
      for (int mm = 0; mm < 17; ++mm) {
        float v = xrow[mcl[mm]];
        if (mm < 2 || mm >= 14) { int m = L0 - 2 + mm; v = (m == mcl[mm]) ? v : 0.0f; }
        xv[mm] = v;
      }
      #pragma unroll
      for (int u = 0; u < 13; ++u) {
        z1[u] = fmaf(w1, xv[u + 2], z1[u]);
        z2[u] = fmaf(w2a[0], xv[u + 1], z2[u]);
        z2[u] = fmaf(w2a[1], xv[u + 2], z2[u]);
        z2[u] = fmaf(w2a[2], xv[u + 3], z2[u]);
        z3[u] = fmaf(w3a[0], xv[u],     z3[u]);
        z3[u] = fmaf(w3a[1], xv[u + 1], z3[u]);
        z3[u] = fmaf(w3a[2], xv[u + 2], z3[u]);
        z3[u] = fmaf(w3a[3], xv[u + 3], z3[u]);
        z3[u] = fmaf(w3a[4], xv[u + 4], z3[u]);
      }
    }
    const float b1v = c1b[o], b2v = c2b[o], b3v = c3b[o];
    float a1 = 0.0f, a2 = 0.0f, a3 = 0.0f;
    #pragma unroll
    for (int u = 0; u < 13; ++u) {
      if (u < NL) {
        int l = L0 + u;
        float v1 = lrelu(z1[u] + b1v);
        float v2 = lrelu(z2[u] + b2v);
        float v3 = lrelu(z3[u] + b3v);
        int f1 = o * LSEQ + l;
        int f2 = (CHN + o) * LSEQ + l;
        int f3 = (2 * CHN + o) * LSEQ + l;
        a1 += v1 * sAT[(f1 / 48) * CHN + ((f1 % 48) & 15)];
        a2 += v2 * sAT[(f2 / 48) * CHN + ((f2 % 48) & 15)];
        a3 += v3 * sAT[(f3 / 48) * CHN + ((f3 % 48) & 15)];
      }
    }
    a1 += __shfl_xor(a1, 16); a1 += __shfl_xor(a1, 32);
    a2 += __shfl_xor(a2, 16); a2 += __shfl_xor(a2, 32);
    a3 += __shfl_xor(a3, 16); a3 += __shfl_xor(a3, 32);
    if (lane < CHN) { sFE[o] = a1; sFE[CHN + o] = a2; sFE[2 * CHN + o] = a3; }
  }
  __syncthreads();
  float* sC = R1;
  if (lane < LSEQ) {
    float colj[HID];
    #pragma unroll
    for (int h = 0; h < HID; ++h) colj[h] = sX4[h * LSEQ + lane];
    *(float4*)(sC + lane * 16)     = make_float4(colj[0], colj[1], colj[2], colj[3]);
    *(float2*)(sC + lane * 16 + 4) = make_float2(colj[4], colj[5]);
    float zs = 0.0f;
    for (int i = 0; i < LSEQ; ++i) {
      const float4 r0 = *(const float4*)(sX4P + i * 8);
      const float2 r1 = *(const float2*)(sX4P + i * 8 + 4);
      float s = r0.x * colj[0];
      s = fmaf(r0.y, colj[1], s); s = fmaf(r0.z, colj[2], s);
      s = fmaf(r0.w, colj[3], s); s = fmaf(r1.x, colj[4], s);
      s = fmaf(r1.y, colj[5], s);
      zs += __expf(s * (1.0f / 6.0f));
    }
    const float zi = frcp(zs);
    const float4 q0 = *(const float4*)(sX4P + lane * 8);
    const float2 q1 = *(const float2*)(sX4P + lane * 8 + 4);
    *(float4*)(sC + lane * 16 + 8)  = make_float4(zi*q0.x, zi*q0.y, zi*q0.z, zi*q0.w);
    *(float2*)(sC + lane * 16 + 12) = make_float2(zi*q1.x, zi*q1.y);
  }
  __syncthreads();
  if (lane < LSEQ) {
    float rowi[HID];
    {
      const float4 q0 = *(const float4*)(sX4P + lane * 8);
      const float2 q1 = *(const float2*)(sX4P + lane * 8 + 4);
      rowi[0] = q0.x; rowi[1] = q0.y; rowi[2] = q0.z;
      rowi[3] = q0.w; rowi[4] = q1.x; rowi[5] = q1.y;
    }
    float ya[HID];
    #pragma unroll
    for (int h = 0; h < HID; ++h) ya[h] = 0.0f;
    for (int j = 0; j < LSEQ; ++j) {
      const float4 t0 = *(const float4*)(sC + j * 16);
      const float2 t1 = *(const float2*)(sC + j * 16 + 4);
      float s = rowi[0] * t0.x;
      s = fmaf(rowi[1], t0.y, s); s = fmaf(rowi[2], t0.z, s);
      s = fmaf(rowi[3], t0.w, s); s = fmaf(rowi[4], t1.x, s);
      s = fmaf(rowi[5], t1.y, s);
      const float e = __expf(s * (1.0f / 6.0f));
      const float4 w0 = *(const float4*)(sC + j * 16 + 8);
      const float2 w1 = *(const float2*)(sC + j * 16 + 12);
      ya[0] = fmaf(e, w0.x, ya[0]);
      ya[1] = fmaf(e, w0.y, ya[1]);
      ya[2] = fmaf(e, w0.z, ya[2]);
      ya[3] = fmaf(e, w0.w, ya[3]);
      ya[4] = fmaf(e, w1.x, ya[4]);
      ya[5] = fmaf(e, w1.y, ya[5]);
    }
    *(float2*)(sY + lane * 6)     = make_float2(ya[0], ya[1]);
    *(float2*)(sY + lane * 6 + 2) = make_float2(ya[2], ya[3]);
    *(float2*)(sY + lane * 6 + 4) = make_float2(ya[4], ya[5]);
  }
  __syncthreads();
  if (lane < HID) {
    float s = 0.0f;
    for (int m = 0; m < LSEQ; ++m) s += sY[lane * LSEQ + m];
    sFE[48 + lane] = s;
  }
  __syncthreads();
  if (lane < 2) {
    float acc = fc3b[lane];
    const float* wr = fc3w + lane * 54;
    #pragma unroll
    for (int k = 0; k < 54; ++k) acc = fmaf(wr[k], sFE[k], acc);
    out[(size_t)b * 2 + lane] = acc;
  }
}

extern "C" void kernel_launch(void* const* d_in, const int* in_sizes, int n_in,
                              void* d_out, int out_size, void* d_ws, size_t ws_size,
                              hipStream_t stream) {
  (void)in_sizes; (void)n_in; (void)out_size;
  const float* x      = (const float*)d_in[0];
  const float* we_w   = (const float*)d_in[1];
  const float* we_b   = (const float*)d_in[2];
  const float* attn_w = (const float*)d_in[3];
  const float* attn_b = (const float*)d_in[4];
  const float* c1w    = (const float*)d_in[5];
  const float* c1b    = (const float*)d_in[6];
  const float* c2w    = (const float*)d_in[7];
  const float* c2b    = (const float*)d_in[8];
  const float* c3w    = (const float*)d_in[9];
  const float* c3b    = (const float*)d_in[10];
  const float* wih    = (const float*)d_in[11];
  const float* whh    = (const float*)d_in[12];
  const float* bih    = (const float*)d_in[13];
  const float* bhh    = (const float*)d_in[14];
  const float* fc3w   = (const float*)d_in[15];
  const float* fc3b   = (const float*)d_in[16];
  float* out = (float*)d_out;

  const size_t gi_elems = (size_t)BATCH * LSEQ * 20;  // 65.5 MB
  const size_t x4_elems = (size_t)BATCH * LSEQ * HID; // 19.7 MB
  const size_t need = (gi_elems + x4_elems) * sizeof(float);

  if (ws_size >= need) {
    float* gig = (float*)d_ws;
    float* x4g = gig + gi_elems;
    k_embed<<<(BATCH * LSEQ) / 256, 256, 0, stream>>>(x, we_w, we_b, wih, bih, gig);
    k_gru<<<BATCH / 64, 64, 0, stream>>>(gig, whh, bhh, x4g);
    k_tail<<<BATCH / 4, 256, 0, stream>>>(x, x4g, we_w, we_b, attn_w, attn_b,
                                          c1w, c1b, c2w, c2b, c3w, c3b,
                                          fc3w, fc3b, out);
  } else {
    fused_kernel<<<BATCH / 4, 256, 0, stream>>>(
        x, we_w, we_b, attn_w, attn_b, c1w, c1b, c2w, c2b, c3w, c3b,
        wih, whh, bih, bhh, fc3w, fc3b, out);
  }
}